// Round 4
// baseline (60.709 us; speedup 1.0000x reference)
//
#include <hip/hip_runtime.h>
#include <hip/hip_bf16.h>
#include <cstdint>
#include <cstddef>

#define NS 2560
#define NQ 8192
#define NC 512
#define DD 1600

typedef __bf16 bf16_t;
typedef __bf16 bf16x4 __attribute__((ext_vector_type(4)));
typedef __bf16 bf16x8 __attribute__((ext_vector_type(8)));
typedef float f32x4 __attribute__((ext_vector_type(4)));

// ---------------------------------------------------------------------------
// Kernel 1: class-mean prototypes (bf16) + ||p||^2 (fp32). One block per class.
// ---------------------------------------------------------------------------
__global__ __launch_bounds__(256) void proto_kernel(
    const float* __restrict__ sup, const int* __restrict__ lab,
    bf16_t* __restrict__ protos, float* __restrict__ p2)
{
    const int m   = blockIdx.x;
    const int tid = threadIdx.x;
    __shared__ int   idxs[32];
    __shared__ int   cnt;
    __shared__ float wsum[4];
    if (tid == 0) cnt = 0;
    __syncthreads();
    for (int i = tid; i < NS; i += 256) {
        if (lab[i] == m) {
            int p = atomicAdd(&cnt, 1);
            if (p < 32) idxs[p] = i;
        }
    }
    __syncthreads();
    int n = cnt < 32 ? cnt : 32;
    if (tid == 0 && n > 1) {                       // deterministic order
        for (int a = 1; a < n; ++a) {
            int key = idxs[a]; int b = a - 1;
            while (b >= 0 && idxs[b] > key) { idxs[b+1] = idxs[b]; --b; }
            idxs[b+1] = key;
        }
    }
    __syncthreads();

    float acc[7];
    #pragma unroll
    for (int u = 0; u < 7; ++u) acc[u] = 0.f;
    for (int t = 0; t < n; ++t) {
        const float* src = sup + (size_t)idxs[t] * DD;
        #pragma unroll
        for (int u = 0; u < 7; ++u) {
            int j = tid + u * 256;
            if (j < DD) acc[u] += src[j];
        }
    }
    float inv = (n > 0) ? 1.f / (float)n : 0.f;
    float psq = 0.f;
    #pragma unroll
    for (int u = 0; u < 7; ++u) {
        int j = tid + u * 256;
        if (j < DD) {
            float p = acc[u] * inv;
            bf16_t pb = (bf16_t)p;
            protos[(size_t)m * DD + j] = pb;
            float pf = (float)pb;
            psq += pf * pf;
        }
    }
    #pragma unroll
    for (int o = 32; o > 0; o >>= 1) psq += __shfl_xor(psq, o);
    int lane = tid & 63, wid = tid >> 6;
    if (lane == 0) wsum[wid] = psq;
    __syncthreads();
    if (tid == 0) p2[m] = wsum[0] + wsum[1] + wsum[2] + wsum[3];
}

// ---------------------------------------------------------------------------
// Per-WAVE B staging: 64 cols x 64 K bf16 (8 KB) into this wave's private
// strip. Linear LDS dest (wave-uniform base + lane*16) + pre-swizzled global
// source (inverse of the read-side XOR swizzle). 8 global_load_lds / wave.
// ---------------------------------------------------------------------------
__device__ __forceinline__ void stage_B_wave(const bf16_t* __restrict__ protos,
                                             char* strip, int k0, int lane, int wid)
{
    #pragma unroll
    for (int p = 0; p < 8; ++p) {
        int gidx = p * 64 + lane;             // 16B granule in strip [0,512)
        int row  = gidx >> 3;                 // strip-local col 0..63
        int gcol = gidx & 7;
        const bf16_t* src = protos + (size_t)(wid * 64 + row) * DD + k0
                          + ((gcol ^ (row & 7)) * 8);
        char* dst = strip + p * 1024;         // wave-uniform; HW adds lane*16
        __builtin_amdgcn_global_load_lds(
            (const __attribute__((address_space(1))) void*)src,
            (__attribute__((address_space(3))) void*)dst, 16, 0, 0);
    }
}

// ---------------------------------------------------------------------------
// Kernel 2 (fused, wave-async pipeline): 32 query rows x ALL 512 classes per
// block; K=1600 in 25 steps of BK=64. Wave w owns cols [w*64,w*64+64):
//   B: wave-PRIVATE double-buffered strips (2 x 8 waves x 8 KB = 128 KB),
//      no barrier needed; counted vmcnt keeps next tile in flight.
//   A: shared 32x64 tile, dbuf 2x4 KB, reg-staged fp32->bf16; raw s_barrier
//      (NO vmcnt drain) + lgkmcnt(0) for visibility.
// Issue order per iter: fA(t+1) load, B(t+1)x8 gload_lds, s_waitcnt vmcnt(9)
// (B(t) done, 9 newer stay in flight), ds_read+16 MFMA, cvt fA (auto
// vmcnt(8)), ds_write A(t+1), lgkmcnt(0), raw s_barrier.
// Epilogue: logits = 2*dot - |p|^2, fused row log_softmax.
// ---------------------------------------------------------------------------
__global__ __launch_bounds__(512, 2) void fused_kernel(
    const float* __restrict__ q, const bf16_t* __restrict__ protos,
    const float* __restrict__ p2, float* __restrict__ out)
{
    extern __shared__ char smem[];
    // [buf][wave][8192] B strips; A at 131072 + buf*4096

    const int tid  = threadIdx.x;
    const int lane = tid & 63;
    const int wid  = tid >> 6;        // wave = 64-col strip 0..7
    const int r    = lane & 15;
    const int g    = lane >> 4;
    const int m0   = blockIdx.x * 32;

    float p2c[4];
    #pragma unroll
    for (int ni = 0; ni < 4; ++ni) p2c[ni] = p2[wid * 64 + ni * 16 + r];

    f32x4 acc[2][4];
    #pragma unroll
    for (int mi = 0; mi < 2; ++mi)
        #pragma unroll
        for (int ni = 0; ni < 4; ++ni)
            acc[mi][ni] = (f32x4){0.f, 0.f, 0.f, 0.f};

    const int arow = tid >> 4;        // 0..31
    const int acg  = tid & 15;        // 4-float column group
    const float* aptr = q + (size_t)(m0 + arow) * DD + acg * 4;
    const int    aoff = (arow * 128 + acg * 8) ^ ((arow & 7) << 4);

    // ---- prologue: A(0) load first (older), then B(0); cvt waits vmcnt(8) ----
    {
        float4 f = *(const float4*)(aptr);
        __builtin_amdgcn_sched_barrier(0);
        stage_B_wave(protos, smem + wid * 8192, 0, lane, wid);
        __builtin_amdgcn_sched_barrier(0);
        bf16x4 w;
        w[0] = (bf16_t)f.x; w[1] = (bf16_t)f.y; w[2] = (bf16_t)f.z; w[3] = (bf16_t)f.w;
        *(bf16x4*)(smem + 131072 + aoff) = w;
        asm volatile("s_waitcnt lgkmcnt(0)" ::: "memory");
        __builtin_amdgcn_sched_barrier(0);
        __builtin_amdgcn_s_barrier();
        __builtin_amdgcn_sched_barrier(0);
    }

    for (int t = 0; t < 25; ++t) {
        const int cur = t & 1;
        const char* bstrip  = smem + cur * 65536 + wid * 8192;
        char*       bstripn = smem + (cur ^ 1) * 65536 + wid * 8192;
        const char* as      = smem + 131072 + cur * 4096;
        char*       asn     = smem + 131072 + (cur ^ 1) * 4096;
        const bool  pre     = (t < 24);

        // ---- issue next tile: fA FIRST (older), then B gloads ----
        float4 fA;
        if (pre) fA = *(const float4*)(aptr + (t + 1) * 64);
        __builtin_amdgcn_sched_barrier(0);
        if (pre) stage_B_wave(protos, bstripn, (t + 1) * 64, lane, wid);
        __builtin_amdgcn_sched_barrier(0);

        // ---- B(t) completion: exactly 9 newer ops (fA + 8 gloads) in flight ----
        if (pre) asm volatile("s_waitcnt vmcnt(9)" ::: "memory");
        else     asm volatile("s_waitcnt vmcnt(0)" ::: "memory");
        __builtin_amdgcn_sched_barrier(0);

        // ---- compute current tile: 2 K-slices of 32 ----
        #pragma unroll
        for (int kk = 0; kk < 2; ++kk) {
            bf16x8 af[2], bfr[4];
            #pragma unroll
            for (int mi = 0; mi < 2; ++mi) {
                int ab = ((mi * 16 + r) * 128 + kk * 64 + g * 16) ^ ((r & 7) << 4);
                af[mi] = *(const bf16x8*)(as + ab);
            }
            #pragma unroll
            for (int ni = 0; ni < 4; ++ni) {
                int c  = ni * 16 + r;          // strip-local col
                int bb = (c * 128 + kk * 64 + g * 16) ^ ((c & 7) << 4);
                bfr[ni] = *(const bf16x8*)(bstrip + bb);
            }
            #pragma unroll
            for (int mi = 0; mi < 2; ++mi)
                #pragma unroll
                for (int ni = 0; ni < 4; ++ni)
                    acc[mi][ni] = __builtin_amdgcn_mfma_f32_16x16x32_bf16(
                        af[mi], bfr[ni], acc[mi][ni], 0, 0, 0);
        }

        // ---- convert + write A(t+1) (auto vmcnt(8): B(t+1) stays in flight) ----
        if (pre) {
            bf16x4 w;
            w[0] = (bf16_t)fA.x; w[1] = (bf16_t)fA.y;
            w[2] = (bf16_t)fA.z; w[3] = (bf16_t)fA.w;
            *(bf16x4*)(asn + aoff) = w;
        }
        asm volatile("s_waitcnt lgkmcnt(0)" ::: "memory");
        __builtin_amdgcn_sched_barrier(0);
        __builtin_amdgcn_s_barrier();          // raw: NO vmcnt drain
        __builtin_amdgcn_sched_barrier(0);
    }

    // ---- logits = 2*dot - |p|^2 ----
    #pragma unroll
    for (int mi = 0; mi < 2; ++mi)
        #pragma unroll
        for (int ni = 0; ni < 4; ++ni)
            #pragma unroll
            for (int j = 0; j < 4; ++j)
                acc[mi][ni][j] = 2.f * acc[mi][ni][j] - p2c[ni];

    // ---- fused log_softmax over 512 cols (scratch overlays B; final raw
    //      barrier above guarantees all LDS reads completed) ----
    float* red  = (float*)smem;   // [32][8]
    float* gmax = red + 256;      // [32]
    float* lse  = gmax + 32;      // [32]

    float rmax[2][4];
    #pragma unroll
    for (int mi = 0; mi < 2; ++mi)
        #pragma unroll
        for (int j = 0; j < 4; ++j) {
            float m = acc[mi][0][j];
            #pragma unroll
            for (int ni = 1; ni < 4; ++ni) m = fmaxf(m, acc[mi][ni][j]);
            rmax[mi][j] = m;
        }
    #pragma unroll
    for (int o = 1; o < 16; o <<= 1)
        #pragma unroll
        for (int mi = 0; mi < 2; ++mi)
            #pragma unroll
            for (int j = 0; j < 4; ++j)
                rmax[mi][j] = fmaxf(rmax[mi][j], __shfl_xor(rmax[mi][j], o));
    if (r == 0) {
        #pragma unroll
        for (int mi = 0; mi < 2; ++mi)
            #pragma unroll
            for (int j = 0; j < 4; ++j)
                red[(mi * 16 + g * 4 + j) * 8 + wid] = rmax[mi][j];
    }
    __syncthreads();
    if (tid < 32) {
        float m = red[tid * 8];
        #pragma unroll
        for (int w = 1; w < 8; ++w) m = fmaxf(m, red[tid * 8 + w]);
        gmax[tid] = m;
    }
    __syncthreads();

    float rsum[2][4];
    #pragma unroll
    for (int mi = 0; mi < 2; ++mi)
        #pragma unroll
        for (int j = 0; j < 4; ++j) {
            float gm = gmax[mi * 16 + g * 4 + j];
            float s = 0.f;
            #pragma unroll
            for (int ni = 0; ni < 4; ++ni) s += expf(acc[mi][ni][j] - gm);
            rsum[mi][j] = s;
        }
    #pragma unroll
    for (int o = 1; o < 16; o <<= 1)
        #pragma unroll
        for (int mi = 0; mi < 2; ++mi)
            #pragma unroll
            for (int j = 0; j < 4; ++j)
                rsum[mi][j] += __shfl_xor(rsum[mi][j], o);
    if (r == 0) {
        #pragma unroll
        for (int mi = 0; mi < 2; ++mi)
            #pragma unroll
            for (int j = 0; j < 4; ++j)
                red[(mi * 16 + g * 4 + j) * 8 + wid] = rsum[mi][j];
    }
    __syncthreads();
    if (tid < 32) {
        float s = 0.f;
        #pragma unroll
        for (int w = 0; w < 8; ++w) s += red[tid * 8 + w];
        lse[tid] = gmax[tid] + logf(s);
    }
    __syncthreads();

    // ---- write output ----
    #pragma unroll
    for (int mi = 0; mi < 2; ++mi) {
        #pragma unroll
        for (int j = 0; j < 4; ++j) {
            float l = lse[mi * 16 + g * 4 + j];
            size_t rowoff = (size_t)(m0 + mi * 16 + g * 4 + j) * NC;
            #pragma unroll
            for (int ni = 0; ni < 4; ++ni)
                out[rowoff + wid * 64 + ni * 16 + r] = acc[mi][ni][j] - l;
        }
    }
}

// ---------------------------------------------------------------------------
extern "C" void kernel_launch(void* const* d_in, const int* in_sizes, int n_in,
                              void* d_out, int out_size, void* d_ws, size_t ws_size,
                              hipStream_t stream)
{
    const float* sup = (const float*)d_in[0];   // [2560,64,5,5]
    const float* qry = (const float*)d_in[1];   // [8192,64,5,5]
    const int*   lab = (const int*)d_in[2];     // [2560]
    float* out = (float*)d_out;                 // [8192,512]

    char* ws = (char*)d_ws;
    bf16_t* protos = (bf16_t*)ws;               // 512*1600*2 = 1,638,400 B
    float*  p2     = (float*)(ws + 1638400);    // 2 KB

    const int smem_bytes = 139264;              // 2x64KB B strips + 2x4KB A
    hipFuncSetAttribute(reinterpret_cast<const void*>(fused_kernel),
                        hipFuncAttributeMaxDynamicSharedMemorySize, smem_bytes);

    proto_kernel<<<NC, 256, 0, stream>>>(sup, lab, protos, p2);
    fused_kernel<<<NQ / 32, 512, smem_bytes, stream>>>(qry, protos, p2, out);
}